// Round 10
// baseline (212.877 us; speedup 1.0000x reference)
//
#include <hip/hip_runtime.h>
#include <hip/hip_bf16.h>
#include <cstdint>

// Problem constants (reference: B=2, T=2048, D=1024, H=16, hd=64, rank=32)
#define NB 2
#define NT 2048
#define ND 1024
#define NH 16
#define HD 64
#define RANK 32
#define HR 512     // NH*RANK
#define ZSTR 1024  // packed zq|zk row stride (f16)

typedef _Float16 f16;
typedef _Float16 f16x2 __attribute__((ext_vector_type(2)));
typedef _Float16 f16x4 __attribute__((ext_vector_type(4)));
typedef _Float16 f16x8 __attribute__((ext_vector_type(8)));
typedef float f32x4 __attribute__((ext_vector_type(4)));

// 1/sqrt(32) * log2(e): QK^T scores come out in log2 domain -> exp2 directly.
#define ZQ_SCALE 0.2550696805f

__device__ __forceinline__ float fast_exp2(float x) {
#if __has_builtin(__builtin_amdgcn_exp2f)
  return __builtin_amdgcn_exp2f(x);
#else
  return exp2f(x);
#endif
}

// ---------------------------------------------------------------------------
// fp32 -> fp16 converter, 8 elems/thread
// ---------------------------------------------------------------------------
__global__ __launch_bounds__(256) void conv_f16(const float* __restrict__ in,
                                                f16* __restrict__ out, int n8) {
  int i = blockIdx.x * 256 + threadIdx.x;
  if (i >= n8) return;
  const float4* p = (const float4*)in + (size_t)i * 2;
  float4 a = p[0], b = p[1];
  f16x8 h = {(f16)a.x, (f16)a.y, (f16)a.z, (f16)a.w,
             (f16)b.x, (f16)b.y, (f16)b.z, (f16)b.w};
  *(f16x8*)(out + (size_t)i * 8) = h;
}

// ---------------------------------------------------------------------------
// Folded projection weights + biases (bias fused: blockIdx.x==0, tid<32).
// Wp[m][h*32+r][D'] = scale_m * sum_d W[h*64+d][D'] * V[d][r]
// grid (4 D'-chunks, 16 h, 3 mats), 256 threads.
// ---------------------------------------------------------------------------
__global__ __launch_bounds__(256) void prep_wp(
    const float* __restrict__ Wq, const float* __restrict__ Wk,
    const float* __restrict__ Wv, const float* __restrict__ V,
    const float* __restrict__ bq, const float* __restrict__ bk,
    const float* __restrict__ bv,
    f16* __restrict__ Oq, f16* __restrict__ Ok, f16* __restrict__ Ov,
    float* __restrict__ bqp, float* __restrict__ bkp, float* __restrict__ bvp)
{
  __shared__ float Vs[HD][RANK];
  const int tid = threadIdx.x;
  const int Dp  = blockIdx.x * 256 + tid;
  const int h   = blockIdx.y;
  const int m   = blockIdx.z;
  const float* W = m == 0 ? Wq : m == 1 ? Wk : Wv;
  f16*         O = m == 0 ? Oq : m == 1 ? Ok : Ov;
  const float scale = m == 0 ? ZQ_SCALE : 1.0f;

  for (int i = tid; i < HD * RANK; i += 256) Vs[i >> 5][i & 31] = V[i];
  __syncthreads();

  float acc[RANK] = {};
#pragma unroll 4
  for (int d = 0; d < HD; ++d) {
    float w = W[(size_t)(h * HD + d) * ND + Dp];  // coalesced across tid
#pragma unroll
    for (int r = 0; r < RANK; ++r) acc[r] = fmaf(w, Vs[d][r], acc[r]);
  }
#pragma unroll
  for (int r = 0; r < RANK; ++r)
    O[(size_t)(h * RANK + r) * ND + Dp] = (f16)(acc[r] * scale);

  if (blockIdx.x == 0 && tid < RANK) {
    const float* bs = m == 0 ? bq : m == 1 ? bk : bv;
    float*       o  = m == 0 ? bqp : m == 1 ? bkp : bvp;
    float a = 0.f;
#pragma unroll
    for (int d = 0; d < HD; ++d) a = fmaf(bs[h * HD + d], Vs[d][tid], a);
    o[h * RANK + tid] = a * scale;
  }
}

// ---------------------------------------------------------------------------
// Folded output weights: WoPP[n][h*32+r] = sum_d Wo[n][h*64+d] * U[d][r]
// grid (16 n-blocks of 64, 16 h).
// ---------------------------------------------------------------------------
__global__ __launch_bounds__(256) void prep_wo(
    const float* __restrict__ Wo, const float* __restrict__ U,
    f16* __restrict__ WoPP)  // [1024][512] f16
{
  __shared__ float Ws[64][65];
  __shared__ float Us[HD][RANK];
  const int tid = threadIdx.x;
  const int n0  = blockIdx.x * 64;
  const int h   = blockIdx.y;

  for (int i = tid; i < HD * RANK; i += 256) Us[i >> 5][i & 31] = U[i];
#pragma unroll
  for (int it = 0; it < 16; ++it) {
    int idx = it * 256 + tid;
    int i = idx >> 6, d = idx & 63;
    Ws[i][d] = Wo[(size_t)(n0 + i) * ND + h * HD + d];
  }
  __syncthreads();

  const int i  = tid >> 2;
  const int r0 = (tid & 3) << 3;
  float acc[8] = {};
#pragma unroll 4
  for (int d = 0; d < HD; ++d) {
    float w = Ws[i][d];
#pragma unroll
    for (int j = 0; j < 8; ++j) acc[j] = fmaf(w, Us[d][r0 + j], acc[j]);
  }
  f16x8 o = {(f16)acc[0], (f16)acc[1], (f16)acc[2], (f16)acc[3],
             (f16)acc[4], (f16)acc[5], (f16)acc[6], (f16)acc[7]};
  *(f16x8*)(WoPP + (size_t)(n0 + i) * HR + h * RANK + r0) = o;
}

// ---------------------------------------------------------------------------
// fp16 MFMA GEMM: C[M,N] = A[M,K] @ W[N,K]^T + bias.
// 128x128 tile (m97 geometry), BK=64, 4 waves each owning a 64x64 out tile,
// acc[4][4], mfma_f32_16x16x32_f16. Staging/swizzle identical to the
// rounds-2..9 verified 128x64 kernel (sB simply grows to 128 rows).
// ---------------------------------------------------------------------------
#define GBM 128
#define GBN 128
#define GBK 64

__device__ __forceinline__ int swz(int b) { return b ^ (((b >> 7) & 7) << 4); }

__device__ __forceinline__ void gload16(const f16* g, const f16* lds_wave_base) {
  __builtin_amdgcn_global_load_lds(
      (const __attribute__((address_space(1))) void*)g,
      (__attribute__((address_space(3))) void*)lds_wave_base, 16, 0, 0);
}

template <typename OT, bool ROWBIAS>
__global__ __launch_bounds__(256) void gemm_f16_bias(
    const f16* __restrict__ A, const f16* __restrict__ W,
    const float* __restrict__ bias, OT* __restrict__ C, int M, int N, int K)
{
  __shared__ f16 sA[GBM * GBK];  // 16 KB
  __shared__ f16 sB[GBN * GBK];  // 16 KB
  const int tid  = threadIdx.x;
  const int wid  = tid >> 6;
  const int lane = tid & 63;
  const int bm = blockIdx.x * GBM;
  const int bn = blockIdx.y * GBN;
  const int wm = (wid >> 1) * 64;
  const int wn = (wid & 1) * 64;

  f32x4 acc[4][4];
#pragma unroll
  for (int i = 0; i < 4; ++i)
#pragma unroll
    for (int j = 0; j < 4; ++j) acc[i][j] = (f32x4){0.f, 0.f, 0.f, 0.f};

  int grow[4], goff[4];
#pragma unroll
  for (int i = 0; i < 4; ++i) {
    int Lg = swz(i * 4096 + tid * 16);
    grow[i] = Lg >> 7;
    goff[i] = (Lg & 127) >> 1;
  }

  const char* sAc = (const char*)sA;
  const char* sBc = (const char*)sB;

  for (int k0 = 0; k0 < K; k0 += GBK) {
    __syncthreads();
#pragma unroll
    for (int i = 0; i < 4; ++i)
      gload16(A + (size_t)(bm + grow[i]) * K + k0 + goff[i],
              (const f16*)((const char*)sA + i * 4096 + wid * 1024));
#pragma unroll
    for (int i = 0; i < 4; ++i)
      gload16(W + (size_t)(bn + grow[i]) * K + k0 + goff[i],
              (const f16*)((const char*)sB + i * 4096 + wid * 1024));
    __syncthreads();

#pragma unroll
    for (int kh = 0; kh < 2; ++kh) {
      const int kb = kh * 64 + ((lane >> 4) << 4);
      f16x8 af[4], bf[4];
#pragma unroll
      for (int mi = 0; mi < 4; ++mi) {
        int Lg = (wm + mi * 16 + (lane & 15)) * 128 + kb;
        af[mi] = *(const f16x8*)(sAc + swz(Lg));
      }
#pragma unroll
      for (int ni = 0; ni < 4; ++ni) {
        int Lg = (wn + ni * 16 + (lane & 15)) * 128 + kb;
        bf[ni] = *(const f16x8*)(sBc + swz(Lg));
      }
#pragma unroll
      for (int mi = 0; mi < 4; ++mi)
#pragma unroll
        for (int ni = 0; ni < 4; ++ni)
          acc[mi][ni] = __builtin_amdgcn_mfma_f32_16x16x32_f16(
              af[mi], bf[ni], acc[mi][ni], 0, 0, 0);
    }
  }

  const int cl = lane & 15, rh = lane >> 4;
#pragma unroll
  for (int ni = 0; ni < 4; ++ni) {
    const int col = bn + wn + ni * 16 + cl;
    const float cb = ROWBIAS ? 0.f : bias[col];
#pragma unroll
    for (int mi = 0; mi < 4; ++mi) {
      const int r0 = bm + wm + mi * 16 + rh * 4;
#pragma unroll
      for (int r = 0; r < 4; ++r) {
        const float bb = ROWBIAS ? bias[r0 + r] : cb;
        C[(size_t)(r0 + r) * N + col] = (OT)(acc[mi][ni][r] + bb);
      }
    }
  }
}

// ---------------------------------------------------------------------------
// MFMA flash attention, fixed-max softmax (m=0), 32 q-rows per wave.
// Structure = rounds-5..9 verified kernel with a second q-fragment sharing
// the same K-fragment reads (kf amortized over 2x MFMA). QBLK=128/block.
//   zqk: [B,T,1024] (cols 0..511 zq scaled, 512..1023 zk)
//   zvT: [H,32,B,T];  y_rh: [B,T,H,32] f16
// ---------------------------------------------------------------------------
#define QBLK 128
#define KBLK 64
#define SKLD 40  // f16 per zk LDS row (80 B)

__global__ __launch_bounds__(256) void attn_mfma(
    const f16* __restrict__ zqk,
    const f16* __restrict__ zvT,
    f16* __restrict__ y_rh)
{
  __shared__ f16 sK[KBLK * SKLD];    // 5120 B
  __shared__ f16 sVT[RANK * KBLK];   // 4096 B
  __shared__ f16 sP[4][32 * KBLK];   // 16 KB (per-wave 4 KB, rows 0-31)
  __shared__ float sL[4][32];

  const int tid  = threadIdx.x;
  const int wid  = tid >> 6;
  const int lane = tid & 63;
  const int g    = lane >> 4;
  const int m16  = lane & 15;
  const int bh   = blockIdx.y;
  const int b    = bh >> 4;
  const int h    = bh & 15;
  const int q0   = blockIdx.x * QBLK + wid * 32;

  const f16* zqb = zqk + (size_t)b * NT * ZSTR + h * RANK;
  const f16* zkb = zqb + HR;
  const char* zvb = (const char*)zvT;

  f16x8 qfA = *(const f16x8*)(zqb + (size_t)(q0 + m16) * ZSTR + g * 8);
  f16x8 qfB = *(const f16x8*)(zqb + (size_t)(q0 + 16 + m16) * ZSTR + g * 8);

  const int zk_row = tid >> 2, zk_c = tid & 3;
  const int zv_r = tid >> 3;
  const int zv_srcoff = ((tid & 7) * 16) ^ ((zv_r & 7) << 4);
  const size_t zv_rowbase = ((size_t)(h * RANK + zv_r) * NB + b) * (NT * 2);

  f32x4 aA0 = {0.f, 0.f, 0.f, 0.f}, aA1 = {0.f, 0.f, 0.f, 0.f};
  f32x4 aB0 = {0.f, 0.f, 0.f, 0.f}, aB1 = {0.f, 0.f, 0.f, 0.f};
  float lA = 0.f, lB = 0.f;

  char* sPw = (char*)&sP[wid][0];
  char* sVTc = (char*)sVT;
  const int swzq = (m16 & 7) << 4;

  for (int k0 = 0; k0 < NT; k0 += KBLK) {
    f16x8 kreg = *(const f16x8*)(zkb + (size_t)(k0 + zk_row) * ZSTR + zk_c * 8);
    __syncthreads();  // prev iter's sK/sVT reads done
    __builtin_amdgcn_global_load_lds(
        (const __attribute__((address_space(1))) void*)(
            zvb + zv_rowbase + k0 * 2 + zv_srcoff),
        (__attribute__((address_space(3))) void*)(sVTc + wid * 1024), 16, 0, 0);
    *(f16x8*)(sK + zk_row * SKLD + zk_c * 8) = kreg;
    __syncthreads();  // staging visible

    // QK^T + exp2 + P-store per kt tile: kf read once, used by both q-frags.
#pragma unroll
    for (int kt = 0; kt < 4; ++kt) {
      f16x8 kf = *(const f16x8*)(sK + (kt * 16 + m16) * SKLD + g * 8);
      f32x4 z4 = {0.f, 0.f, 0.f, 0.f};
      f32x4 sa = __builtin_amdgcn_mfma_f32_16x16x32_f16(kf, qfA, z4, 0, 0, 0);
      f32x4 sb = __builtin_amdgcn_mfma_f32_16x16x32_f16(kf, qfB, z4, 0, 0, 0);
      float a0 = fast_exp2(sa[0]), a1 = fast_exp2(sa[1]);
      float a2 = fast_exp2(sa[2]), a3 = fast_exp2(sa[3]);
      float b0 = fast_exp2(sb[0]), b1 = fast_exp2(sb[1]);
      float b2 = fast_exp2(sb[2]), b3 = fast_exp2(sb[3]);
      lA += (a0 + a1) + (a2 + a3);
      lB += (b0 + b1) + (b2 + b3);
      const int off = (kt * 32 + g * 8) ^ swzq;
      f16x4 pa = {(f16)a0, (f16)a1, (f16)a2, (f16)a3};
      f16x4 pb = {(f16)b0, (f16)b1, (f16)b2, (f16)b3};
      *(f16x4*)(sPw + m16 * 128 + off)        = pa;
      *(f16x4*)(sPw + (16 + m16) * 128 + off) = pb;
    }

    // PV: A-frags from both P-row sets, B = zvT columns (r and 16+r).
#pragma unroll
    for (int kt2 = 0; kt2 < 2; ++kt2) {
      const int rb = (kt2 * 64 + g * 16) ^ swzq;
      f16x8 pfA = *(const f16x8*)(sPw + m16 * 128 + rb);
      f16x8 pfB = *(const f16x8*)(sPw + (16 + m16) * 128 + rb);
      f16x8 v0 = *(const f16x8*)(sVTc + m16 * 128 + rb);
      f16x8 v1 = *(const f16x8*)(sVTc + (16 + m16) * 128 + rb);
      aA0 = __builtin_amdgcn_mfma_f32_16x16x32_f16(pfA, v0, aA0, 0, 0, 0);
      aA1 = __builtin_amdgcn_mfma_f32_16x16x32_f16(pfA, v1, aA1, 0, 0, 0);
      aB0 = __builtin_amdgcn_mfma_f32_16x16x32_f16(pfB, v0, aB0, 0, 0, 0);
      aB1 = __builtin_amdgcn_mfma_f32_16x16x32_f16(pfB, v1, aB1, 0, 0, 0);
    }
  }

  // final l reduce: sum over the 4 g-lanes holding each q
  lA += __shfl_xor(lA, 16);
  lA += __shfl_xor(lA, 32);
  lB += __shfl_xor(lB, 16);
  lB += __shfl_xor(lB, 32);
  if (lane < 16) {
    sL[wid][lane]      = lA;
    sL[wid][16 + lane] = lB;
  }
  __syncthreads();

  f16* yb = y_rh + ((size_t)(b * NT) + q0) * HR + h * RANK;
#pragma unroll
  for (int r = 0; r < 4; ++r) {
    const int qa = g * 4 + r;
    const float invA = 1.f / sL[wid][qa];
    yb[(size_t)qa * HR + m16]      = (f16)(aA0[r] * invA);
    yb[(size_t)qa * HR + 16 + m16] = (f16)(aA1[r] * invA);
    const int qb2 = 16 + qa;
    const float invB = 1.f / sL[wid][qb2];
    yb[(size_t)qb2 * HR + m16]      = (f16)(aB0[r] * invB);
    yb[(size_t)qb2 * HR + 16 + m16] = (f16)(aB1[r] * invB);
  }
}

// ---------------------------------------------------------------------------
// Workspace layout (f32 units). Total 7,341,568 f32 = 29.4 MB. No aliasing.
// ---------------------------------------------------------------------------
extern "C" void kernel_launch(void* const* d_in, const int* in_sizes, int n_in,
                              void* d_out, int out_size, void* d_ws, size_t ws_size,
                              hipStream_t stream) {
  const float* x  = (const float*)d_in[0];
  const float* Wq = (const float*)d_in[1];
  const float* bq = (const float*)d_in[2];
  const float* Wk = (const float*)d_in[3];
  const float* bk = (const float*)d_in[4];
  const float* Wv = (const float*)d_in[5];
  const float* bv = (const float*)d_in[6];
  const float* Wo = (const float*)d_in[7];
  const float* bo = (const float*)d_in[8];
  const float* U  = (const float*)d_in[9];
  const float* V  = (const float*)d_in[10];
  float* out = (float*)d_out;

  float* ws = (float*)d_ws;
  f16*   x_h   = (f16*)(ws + 0);          // [4096][1024] f16
  f16*   WqkPT = (f16*)(ws + 2097152);    // [1024][1024] f16 (q rows 0-511, k 512-1023)
  f16*   WvPT  = (f16*)(ws + 2621440);    // [512][1024] f16
  f16*   WoPP  = (f16*)(ws + 2883584);    // [1024][512] f16
  float* bqkp  = ws + 3145728;            // [1024] f32
  float* bvp   = ws + 3146752;            // [512] f32
  f16*   zqk   = (f16*)(ws + 3147264);    // [4096][1024] f16
  f16*   zvT   = (f16*)(ws + 5244416);    // [512][4096] f16
  f16*   y_rh  = (f16*)(ws + 6292992);    // [4096][512] f16

  conv_f16<<<2048, 256, 0, stream>>>(x, x_h, 524288);

  prep_wp<<<dim3(4, 16, 3), 256, 0, stream>>>(
      Wq, Wk, Wv, V, bq, bk, bv,
      WqkPT, WqkPT + 512 * 1024, WvPT, bqkp, bqkp + 512, bvp);
  prep_wo<<<dim3(16, 16), 256, 0, stream>>>(Wo, U, WoPP);

  // zqk = x @ [Wq'|Wk'] : [4096 x 1024], K=1024
  gemm_f16_bias<f16, false><<<dim3(32, 8), 256, 0, stream>>>(
      x_h, WqkPT, bqkp, zqk, NB * NT, ZSTR, ND);
  // zvT = Wv'^T @ x^T : [512 x 4096], row-bias
  gemm_f16_bias<f16, true><<<dim3(4, 32), 256, 0, stream>>>(
      WvPT, x_h, bvp, zvT, HR, NB * NT, ND);

  dim3 ga(NT / QBLK, NB * NH);  // (16, 32)
  attn_mfma<<<ga, 256, 0, stream>>>(zqk, zvT, y_rh);

  // out = y_rh @ WoPP^T + bo : K=512
  gemm_f16_bias<float, false><<<dim3(32, 8), 256, 0, stream>>>(
      y_rh, WoPP, bo, out, NB * NT, ND, HR);
}